// Round 1
// baseline (77389.941 us; speedup 1.0000x reference)
//
#include <hip/hip_runtime.h>

// Problem constants (from reference): N=16, T=2048, H=512
#define N_B 16
#define T_S 2048
#define H_D 512
#define TH_STRIDE (T_S * H_D)          // per-batch stride in x/out: 1,048,576
#define NTH ((size_t)N_B * T_S * H_D)  // 16,777,216

// LDS pad for h tile: stride 516 words -> 516%32==4 -> (4n+i) bank spread,
// 2 addrs/bank (free); 516*4=2064 bytes, 16B-aligned rows for float4 reads.
#define HS_PAD 516

__global__ __launch_bounds__(512) void init_kernel(const float* __restrict__ hidden,
                                                   float* __restrict__ hbuf0,
                                                   float* __restrict__ out) {
    int idx = blockIdx.x * blockDim.x + threadIdx.x;
    if (idx < N_B * H_D) {
        float h = hidden[idx];
        hbuf0[idx] = h;
        int n = idx >> 9;
        int j = idx & 511;
        // out[n, 0, :] = initial hidden (pre-update emission at t=0)
        out[(size_t)n * TH_STRIDE + j] = h;
    }
}

// One timestep. 64 blocks x 384 threads. Block b owns output columns
// [b*8, b*8+8). Waves 0-1 compute q, 2-3 compute k, 4-5 compute v
// (wave-uniform matrix select). Thread -> (m, j_local, n):
//   m = tid>>7, r = tid&127, j_local = r>>4, n = r&15.
// Lanes 0..15 of each 16-lane group share (m,j) and differ in n, so the
// weight row load is a 16-lane broadcast and the h-LDS read is bank-spread.
__global__ __launch_bounds__(384) void step_kernel(
    const float* __restrict__ x,
    const float* __restrict__ Wq, const float* __restrict__ bq,
    const float* __restrict__ Wk, const float* __restrict__ bk,
    const float* __restrict__ Wv, const float* __restrict__ bv,
    const float* __restrict__ hcur, float* __restrict__ hnext,
    float* __restrict__ out, int t)
{
    __shared__ float hs[N_B][HS_PAD];
    __shared__ float sh_q[8][16];
    __shared__ float sh_k[8][16];
    __shared__ float sh_v[8][16];

    const int tid = threadIdx.x;

    // Stage current hidden (16x512 fp32 = 32 KB) into LDS, coalesced.
    for (int idx = tid; idx < N_B * H_D; idx += 384) {
        int n = idx >> 9;
        int i = idx & 511;
        hs[n][i] = hcur[idx];
    }
    __syncthreads();

    const int m  = tid >> 7;      // 0=q, 1=k, 2=v  (uniform per wave-pair)
    const int r  = tid & 127;
    const int jl = r >> 4;        // 0..7
    const int n  = r & 15;
    const int j  = blockIdx.x * 8 + jl;   // output column 0..511

    const float* W = (m == 0) ? Wq : (m == 1) ? Wk : Wv;
    const float* b = (m == 0) ? bq : (m == 1) ? bk : bv;

    // Weight row j: [0:512) multiplies x_t, [512:1024) multiplies h.
    const float4* wrow_x = (const float4*)(W + (size_t)j * 1024);
    const float4* wrow_h = wrow_x + 128;
    const float4* xrow   = (const float4*)(x + (size_t)n * TH_STRIDE + (size_t)t * H_D);

    float acc = 0.f;
    // x-part: both streams from global (x_t slice is L1/L2-hot: 16-lane broadcast rows)
    #pragma unroll 8
    for (int i4 = 0; i4 < 128; ++i4) {
        float4 w = wrow_x[i4];
        float4 c = xrow[i4];
        acc = fmaf(w.x, c.x, acc);
        acc = fmaf(w.y, c.y, acc);
        acc = fmaf(w.z, c.z, acc);
        acc = fmaf(w.w, c.w, acc);
    }
    // h-part: h from LDS
    #pragma unroll 8
    for (int i4 = 0; i4 < 128; ++i4) {
        float4 w = wrow_h[i4];
        float4 c = *(const float4*)&hs[n][i4 * 4];
        acc = fmaf(w.x, c.x, acc);
        acc = fmaf(w.y, c.y, acc);
        acc = fmaf(w.z, c.z, acc);
        acc = fmaf(w.w, c.w, acc);
    }
    acc += b[j];

    if (m == 0)      sh_q[jl][n] = acc;
    else if (m == 1) sh_k[jl][n] = acc;
    else             sh_v[jl][n] = acc;
    __syncthreads();

    if (m == 0) {
        float q = sh_q[jl][n];
        float k = sh_k[jl][n];
        float v = sh_v[jl][n];
        float w = 1.f / (1.f + expf(-q * k));
        float hprev = hs[n][j];
        float hn = (1.f - w) * hprev + w * tanhf(v);
        hnext[n * H_D + j] = hn;
        // Emit H_{t+1}: goes to out[:, t+1, :] for t+1 < T, else to h_final tail.
        size_t opos = (t + 1 < T_S)
                    ? ((size_t)n * TH_STRIDE + (size_t)(t + 1) * H_D + j)
                    : (NTH + (size_t)n * H_D + j);
        out[opos] = hn;
    }
}

extern "C" void kernel_launch(void* const* d_in, const int* in_sizes, int n_in,
                              void* d_out, int out_size, void* d_ws, size_t ws_size,
                              hipStream_t stream) {
    const float* x      = (const float*)d_in[0];
    const float* hidden = (const float*)d_in[1];
    const float* Wq     = (const float*)d_in[2];
    const float* bq     = (const float*)d_in[3];
    const float* Wk     = (const float*)d_in[4];
    const float* bk     = (const float*)d_in[5];
    const float* Wv     = (const float*)d_in[6];
    const float* bv     = (const float*)d_in[7];
    float* out = (float*)d_out;

    // Workspace: two ping-pong hidden buffers (16x512 fp32 each = 32 KB).
    float* hb0 = (float*)d_ws;
    float* hb1 = hb0 + N_B * H_D;

    init_kernel<<<(N_B * H_D + 511) / 512, 512, 0, stream>>>(hidden, hb0, out);

    for (int t = 0; t < T_S; ++t) {
        const float* hc = (t & 1) ? hb1 : hb0;
        float*       hn = (t & 1) ? hb0 : hb1;
        step_kernel<<<64, 384, 0, stream>>>(x, Wq, bq, Wk, bk, Wv, bv, hc, hn, out, t);
    }
}

// Round 2
// 52000.140 us; speedup vs baseline: 1.4883x; 1.4883x over previous
//
#include <hip/hip_runtime.h>

// N=16 batches, T=2048 steps, H=512. q|k|v = cat(x_t, h) @ W?.T + b?
// h' = (1-sigmoid(q*k))*h + sigmoid(q*k)*tanh(v)
//
// Persistent cooperative kernel:
//   - 256 WGs x 512 threads, 1 WG/CU.
//   - group g = blockIdx & 15 (= batch). 16 WGs per group (same XCD under
//     round-robin dispatch). Groups are fully independent chains.
//   - WG wm owns rows j = [wm*32, wm*32+32) of all three mats.
//   - thread (rs = tid>>4, ks = tid&15): rows j0 = wm*32+rs, K-slice
//     [ks*64, ks*64+64) of the 1024-long cat dot. Holds 3x64 = 192 weight
//     floats in VGPRs for the whole kernel. 192 FMAs/thread/step.
//   - 16-lane shfl_xor butterfly reduces the K-partials; lane ks==0 applies
//     the gate and writes h_{t+1} straight into out[g, t+1, :] (out IS the
//     h exchange buffer; h_old for the gate stays in a register).
//   - per-group barrier: monotonic counter, release-add / acquire-spin,
//     + agent acquire fence so normal vector loads of h see remote writes.
#define N_B 16
#define T_S 2048
#define H_D 512
#define TH_STRIDE ((size_t)T_S * H_D)
#define NTH ((size_t)N_B * T_S * H_D)
#define WPG 16
#define THREADS 512

__global__ __launch_bounds__(THREADS, 1) void rnn_persist(
    const float* __restrict__ x,
    const float* __restrict__ hidden,
    const float* __restrict__ Wq, const float* __restrict__ bq,
    const float* __restrict__ Wk, const float* __restrict__ bk,
    const float* __restrict__ Wv, const float* __restrict__ bv,
    float* __restrict__ out,
    int* __restrict__ cnt)
{
    const int g    = blockIdx.x & 15;   // batch / sync group
    const int wm   = blockIdx.x >> 4;   // member within group, 0..15
    const int tid  = threadIdx.x;
    const int ks   = tid & 15;          // K-slice index (64 floats each)
    const int rs   = tid >> 4;          // row-set 0..31
    const int j0   = wm * 32 + rs;      // owned output row 0..511
    const int kbase = ks * 64;          // offset into cat[0..1024)

    // ---- pin weights in VGPRs (static indices only -> stays in registers)
    float4 wq[16], wk[16], wv[16];
    {
        const float4* q4 = (const float4*)(Wq + (size_t)j0 * 1024 + kbase);
        const float4* k4 = (const float4*)(Wk + (size_t)j0 * 1024 + kbase);
        const float4* v4 = (const float4*)(Wv + (size_t)j0 * 1024 + kbase);
        #pragma unroll
        for (int c = 0; c < 16; ++c) { wq[c] = q4[c]; wk[c] = k4[c]; wv[c] = v4[c]; }
    }
    const float bqr = bq[j0], bkr = bk[j0], bvr = bv[j0];

    float h_old = hidden[g * H_D + j0];          // thread-local h[g, j0]
    if (ks == 0) out[(size_t)g * TH_STRIDE + j0] = h_old;   // out[g,0,:] = h_0

    const bool  is_x = (ks < 8);
    const float* xb  = x      + (size_t)g * TH_STRIDE + kbase;            // + t*H
    const float* hb0 = hidden + (size_t)g * H_D       + (kbase - 512);    // t==0
    const float* hbt = out    + (size_t)g * TH_STRIDE + (kbase - 512);    // + t*H

    int* mycnt = cnt + g * 64;   // 256B-strided per-group counter

    for (int t = 0; t < T_S; ++t) {
        const float* hs = (t == 0) ? hb0 : (hbt + (size_t)t * H_D);
        const float4* a4 = (const float4*)(is_x ? (xb + (size_t)t * H_D) : hs);

        // ---- 192 FMAs, 2-way split accumulators to halve dep-chain depth
        float q0=0.f,q1=0.f,k0=0.f,k1=0.f,v0=0.f,v1=0.f;
        #pragma unroll
        for (int c = 0; c < 16; c += 2) {
            float4 a = a4[c];
            q0 = fmaf(wq[c].x,a.x,q0); q0 = fmaf(wq[c].y,a.y,q0);
            q0 = fmaf(wq[c].z,a.z,q0); q0 = fmaf(wq[c].w,a.w,q0);
            k0 = fmaf(wk[c].x,a.x,k0); k0 = fmaf(wk[c].y,a.y,k0);
            k0 = fmaf(wk[c].z,a.z,k0); k0 = fmaf(wk[c].w,a.w,k0);
            v0 = fmaf(wv[c].x,a.x,v0); v0 = fmaf(wv[c].y,a.y,v0);
            v0 = fmaf(wv[c].z,a.z,v0); v0 = fmaf(wv[c].w,a.w,v0);
            float4 b = a4[c + 1];
            q1 = fmaf(wq[c+1].x,b.x,q1); q1 = fmaf(wq[c+1].y,b.y,q1);
            q1 = fmaf(wq[c+1].z,b.z,q1); q1 = fmaf(wq[c+1].w,b.w,q1);
            k1 = fmaf(wk[c+1].x,b.x,k1); k1 = fmaf(wk[c+1].y,b.y,k1);
            k1 = fmaf(wk[c+1].z,b.z,k1); k1 = fmaf(wk[c+1].w,b.w,k1);
            v1 = fmaf(wv[c+1].x,b.x,v1); v1 = fmaf(wv[c+1].y,b.y,v1);
            v1 = fmaf(wv[c+1].z,b.z,v1); v1 = fmaf(wv[c+1].w,b.w,v1);
        }
        float accq = q0 + q1, acck = k0 + k1, accv = v0 + v1;

        // ---- reduce K-partials across the 16 ks-lanes (same rs per group)
        #pragma unroll
        for (int m = 1; m < 16; m <<= 1) {
            accq += __shfl_xor(accq, m);
            acck += __shfl_xor(acck, m);
            accv += __shfl_xor(accv, m);
        }

        if (ks == 0) {
            float q = accq + bqr, k = acck + bkr, v = accv + bvr;
            float w  = 1.f / (1.f + expf(-q * k));
            float hn = fmaf(w, tanhf(v) - h_old, h_old);
            size_t opos = (t + 1 < T_S)
                ? ((size_t)g * TH_STRIDE + (size_t)(t + 1) * H_D + j0)
                : (NTH + (size_t)g * H_D + j0);   // h_final tail
            out[opos] = hn;
            h_old = hn;
        }

        // ---- group barrier (monotonic counter; one atomic per WG per step)
        __syncthreads();   // drains this WG's stores (vmcnt(0) before s_barrier)
        if (tid == 0) {
            __hip_atomic_fetch_add(mycnt, 1, __ATOMIC_RELEASE, __HIP_MEMORY_SCOPE_AGENT);
            const int target = WPG * (t + 1);
            while (__hip_atomic_load(mycnt, __ATOMIC_ACQUIRE, __HIP_MEMORY_SCOPE_AGENT) < target)
                __builtin_amdgcn_s_sleep(1);
        }
        __syncthreads();
        // make remote h writes visible to this WG's normal vector loads
        __builtin_amdgcn_fence(__ATOMIC_ACQUIRE, "agent");
    }
}

extern "C" void kernel_launch(void* const* d_in, const int* in_sizes, int n_in,
                              void* d_out, int out_size, void* d_ws, size_t ws_size,
                              hipStream_t stream) {
    const float* x      = (const float*)d_in[0];
    const float* hidden = (const float*)d_in[1];
    const float* Wq     = (const float*)d_in[2];
    const float* bq     = (const float*)d_in[3];
    const float* Wk     = (const float*)d_in[4];
    const float* bk     = (const float*)d_in[5];
    const float* Wv     = (const float*)d_in[6];
    const float* bv     = (const float*)d_in[7];
    float* out = (float*)d_out;
    int*   cnt = (int*)d_ws;   // 16 groups x 64 ints (256B stride) = 4 KB

    hipMemsetAsync(cnt, 0, 16 * 64 * sizeof(int), stream);

    void* args[] = { (void*)&x, (void*)&hidden,
                     (void*)&Wq, (void*)&bq, (void*)&Wk, (void*)&bk,
                     (void*)&Wv, (void*)&bv, (void*)&out, (void*)&cnt };
    hipLaunchCooperativeKernel((const void*)rnn_persist,
                               dim3(N_B * WPG), dim3(THREADS),
                               args, 0, stream);
}

// Round 3
// 10177.686 us; speedup vs baseline: 7.6039x; 5.1092x over previous
//
#include <hip/hip_runtime.h>

// AttentionRnnBlock: N=16, T=2048, H=512.
// q|k|v = cat(x_t, h_t) @ W?.T + b? ; w=sigmoid(q*k); h' = (1-w)h + w tanh(v)
//
// Persistent cooperative kernel, 256 WGs x 512 threads (1 WG/CU).
//  - 8 groups x 32 WGs; group g owns batches {2g, 2g+1}. Under round-robin
//    dispatch all 32 WGs of a group share one XCD, but correctness does NOT
//    depend on it: all cross-WG data moves via agent-scope atomics (PoC).
//  - WG wm owns rows [wm*16, wm*16+16); wave wv owns rows jA=wm*16+2wv, jB=jA+1.
//  - lane (0..63) owns cat-slice [lane*16, lane*16+16). Pinned per-thread
//    weights: 2 rows x 3 mats x 16 floats = 96 floats (24 float4).
//  - per step: 8 swizzled ds_read_b128 of cat -> 192 FMA -> 6-stage shfl_xor
//    reduce (12 values) -> lanes 0..3 apply gate, PoC-store h_{t+1} into
//    out[b, t+1, :] (out IS the exchange buffer; fresh address each step).
//  - barrier: monotonic per-group counter, relaxed agent add/spin; ordering
//    via __syncthreads() vmcnt drain. NO agent fences -> no wbl2/inv.
#define N_B 16
#define T_S 2048
#define H_D 512
#define TH_F ((size_t)T_S * H_D)        // floats per batch in x/out
#define NTH ((size_t)N_B * TH_F)
#define NGROUP 8
#define WPG 32
#define THREADS 512

// f4-granularity LDS swizzle: 2 lanes/bank (free) for lane-strided 64B reads.
__device__ __forceinline__ int swz(int v) {
    return v ^ ((v >> 3) & 7) ^ ((v >> 6) & 3);
}

__global__ __launch_bounds__(THREADS, 2) void rnn_persist(
    const float* __restrict__ x,
    const float* __restrict__ hidden,
    const float* __restrict__ Wq, const float* __restrict__ bq,
    const float* __restrict__ Wk, const float* __restrict__ bk,
    const float* __restrict__ Wv, const float* __restrict__ bv,
    float* __restrict__ out,
    int* __restrict__ cnt)
{
    const int tid  = threadIdx.x;
    const int lane = tid & 63;
    const int wv   = tid >> 6;          // wave 0..7
    const int g    = blockIdx.x & 7;    // group / XCD (heuristic)
    const int wm   = blockIdx.x >> 3;   // member 0..31
    const int b0 = 2 * g, b1 = 2 * g + 1;
    const int jA = wm * 16 + 2 * wv, jB = jA + 1;

    __shared__ float4 cat4[2][256];     // [batch][cat f4], swizzled; 8 KB

    // ---- pin weights: rows jA,jB, slice [lane*16, +16) of each matrix
    float4 wqA[4], wqB[4], wkA[4], wkB[4], wvA[4], wvB[4];
    {
        const float4* qA = (const float4*)(Wq + (size_t)jA * 1024) + lane * 4;
        const float4* qB = (const float4*)(Wq + (size_t)jB * 1024) + lane * 4;
        const float4* kA = (const float4*)(Wk + (size_t)jA * 1024) + lane * 4;
        const float4* kB = (const float4*)(Wk + (size_t)jB * 1024) + lane * 4;
        const float4* vA = (const float4*)(Wv + (size_t)jA * 1024) + lane * 4;
        const float4* vB = (const float4*)(Wv + (size_t)jB * 1024) + lane * 4;
        #pragma unroll
        for (int c = 0; c < 4; ++c) {
            wqA[c] = qA[c]; wqB[c] = qB[c];
            wkA[c] = kA[c]; wkB[c] = kB[c];
            wvA[c] = vA[c]; wvB[c] = vB[c];
        }
    }
    const float bqA = bq[jA], bqB = bq[jB];
    const float bkA = bk[jA], bkB = bk[jB];
    const float bvA = bv[jA], bvB = bv[jB];
    float hoA0 = hidden[b0 * H_D + jA], hoA1 = hidden[b1 * H_D + jA];
    float hoB0 = hidden[b0 * H_D + jB], hoB1 = hidden[b1 * H_D + jB];

    const float4* x4   = (const float4*)x;
    const float4* hid4 = (const float4*)hidden;

    // ---- stage cat for t=0; init out[:,0,:]
    if (tid < 256) {
        const int nb = tid >> 7, u = tid & 127;
        const int b  = nb ? b1 : b0;
        float4 xv = x4[(size_t)b * (TH_F / 4) + u];       // x[b, 0, 4u..]
        float4 hv = hid4[b * 128 + u];
        cat4[nb][swz(u)]       = xv;
        cat4[nb][swz(128 + u)] = hv;
        if (wm == 0) ((float4*)out)[(size_t)b * (TH_F / 4) + u] = hv;
    }
    __syncthreads();

    int* mycnt = cnt + g * 64;
    const int    pre_nb = tid >> 7, pre_u = tid & 127;
    const size_t pre_xb = (size_t)(pre_nb ? b1 : b0) * (TH_F / 4) + pre_u;
    const int    h_nb = tid >> 8, h_f = (tid & 255) * 2;
    const int    h_b  = h_nb ? b1 : b0;

    for (int t = 0; t < T_S; ++t) {
        const bool do_next = (t + 1 < T_S);

        // prefetch x_{t+1} into regs (waves 0-3); drains under compute
        float4 xpre = make_float4(0.f, 0.f, 0.f, 0.f);
        if (do_next && tid < 256) xpre = x4[pre_xb + (size_t)(t + 1) * 128];

        // ---- 192 FMAs from 8 swizzled ds_read_b128
        float acc[2][3][2];   // [row A/B][q/k/v][batch]
        #pragma unroll
        for (int r = 0; r < 2; ++r)
            #pragma unroll
            for (int m = 0; m < 3; ++m)
                #pragma unroll
                for (int nb = 0; nb < 2; ++nb) acc[r][m][nb] = 0.f;
        #pragma unroll
        for (int nb = 0; nb < 2; ++nb) {
            #pragma unroll
            for (int c = 0; c < 4; ++c) {
                const float4 a = cat4[nb][swz(lane * 4 + c)];
                acc[0][0][nb] = fmaf(wqA[c].x, a.x, acc[0][0][nb]);
                acc[0][0][nb] = fmaf(wqA[c].y, a.y, acc[0][0][nb]);
                acc[0][0][nb] = fmaf(wqA[c].z, a.z, acc[0][0][nb]);
                acc[0][0][nb] = fmaf(wqA[c].w, a.w, acc[0][0][nb]);
                acc[0][1][nb] = fmaf(wkA[c].x, a.x, acc[0][1][nb]);
                acc[0][1][nb] = fmaf(wkA[c].y, a.y, acc[0][1][nb]);
                acc[0][1][nb] = fmaf(wkA[c].z, a.z, acc[0][1][nb]);
                acc[0][1][nb] = fmaf(wkA[c].w, a.w, acc[0][1][nb]);
                acc[0][2][nb] = fmaf(wvA[c].x, a.x, acc[0][2][nb]);
                acc[0][2][nb] = fmaf(wvA[c].y, a.y, acc[0][2][nb]);
                acc[0][2][nb] = fmaf(wvA[c].z, a.z, acc[0][2][nb]);
                acc[0][2][nb] = fmaf(wvA[c].w, a.w, acc[0][2][nb]);
                acc[1][0][nb] = fmaf(wqB[c].x, a.x, acc[1][0][nb]);
                acc[1][0][nb] = fmaf(wqB[c].y, a.y, acc[1][0][nb]);
                acc[1][0][nb] = fmaf(wqB[c].z, a.z, acc[1][0][nb]);
                acc[1][0][nb] = fmaf(wqB[c].w, a.w, acc[1][0][nb]);
                acc[1][1][nb] = fmaf(wkB[c].x, a.x, acc[1][1][nb]);
                acc[1][1][nb] = fmaf(wkB[c].y, a.y, acc[1][1][nb]);
                acc[1][1][nb] = fmaf(wkB[c].z, a.z, acc[1][1][nb]);
                acc[1][1][nb] = fmaf(wkB[c].w, a.w, acc[1][1][nb]);
                acc[1][2][nb] = fmaf(wvB[c].x, a.x, acc[1][2][nb]);
                acc[1][2][nb] = fmaf(wvB[c].y, a.y, acc[1][2][nb]);
                acc[1][2][nb] = fmaf(wvB[c].z, a.z, acc[1][2][nb]);
                acc[1][2][nb] = fmaf(wvB[c].w, a.w, acc[1][2][nb]);
            }
        }

        // ---- full-wave reduce: every lane ends with all 12 totals
        #pragma unroll
        for (int m = 1; m < 64; m <<= 1) {
            #pragma unroll
            for (int r = 0; r < 2; ++r)
                #pragma unroll
                for (int mm = 0; mm < 3; ++mm)
                    #pragma unroll
                    for (int nb = 0; nb < 2; ++nb)
                        acc[r][mm][nb] += __shfl_xor(acc[r][mm][nb], m);
        }

        // ---- writers: lane0=(jA,b0) lane1=(jA,b1) lane2=(jB,b0) lane3=(jB,b1)
        if (lane < 4) {
            float q, k, vv, ho, bbq, bbk, bbv; int j, b;
            if (lane == 0)      { q=acc[0][0][0]; k=acc[0][1][0]; vv=acc[0][2][0]; ho=hoA0; bbq=bqA; bbk=bkA; bbv=bvA; j=jA; b=b0; }
            else if (lane == 1) { q=acc[0][0][1]; k=acc[0][1][1]; vv=acc[0][2][1]; ho=hoA1; bbq=bqA; bbk=bkA; bbv=bvA; j=jA; b=b1; }
            else if (lane == 2) { q=acc[1][0][0]; k=acc[1][1][0]; vv=acc[1][2][0]; ho=hoB0; bbq=bqB; bbk=bkB; bbv=bvB; j=jB; b=b0; }
            else                { q=acc[1][0][1]; k=acc[1][1][1]; vv=acc[1][2][1]; ho=hoB1; bbq=bqB; bbk=bkB; bbv=bvB; j=jB; b=b1; }
            q += bbq; k += bbk; vv += bbv;
            const float w  = 1.f / (1.f + expf(-q * k));
            const float hn = fmaf(w, tanhf(vv) - ho, ho);
            const size_t opos = do_next
                ? ((size_t)b * TH_F + (size_t)(t + 1) * H_D + j)
                : (NTH + (size_t)b * H_D + j);                   // h_final tail
            __hip_atomic_store(out + opos, hn, __ATOMIC_RELAXED, __HIP_MEMORY_SCOPE_AGENT);
            if (lane == 0) hoA0 = hn; else if (lane == 1) hoA1 = hn;
            else if (lane == 2) hoB0 = hn; else hoB1 = hn;
        }

        __syncthreads();   // vmcnt(0) drain: hn PoC stores complete before add

        if (do_next) {
            if (tid == 0) {
                __hip_atomic_fetch_add(mycnt, 1, __ATOMIC_RELAXED, __HIP_MEMORY_SCOPE_AGENT);
                const int target = WPG * (t + 1);
                while (__hip_atomic_load(mycnt, __ATOMIC_RELAXED, __HIP_MEMORY_SCOPE_AGENT) < target) {}
            }
            __syncthreads();
            // restage cat: x from prefetch regs, h via PoC loads of out[:,t+1,:]
            if (tid < 256) cat4[pre_nb][swz(pre_u)] = xpre;
            {
                const float* hsrc = out + (size_t)h_b * TH_F + (size_t)(t + 1) * H_D + h_f;
                float v0 = __hip_atomic_load(hsrc,     __ATOMIC_RELAXED, __HIP_MEMORY_SCOPE_AGENT);
                float v1 = __hip_atomic_load(hsrc + 1, __ATOMIC_RELAXED, __HIP_MEMORY_SCOPE_AGENT);
                float* slot = (float*)&cat4[h_nb][swz(128 + (h_f >> 2))];
                slot[(h_f & 3)]     = v0;
                slot[(h_f & 3) + 1] = v1;
            }
            __syncthreads();
        }
    }
}

extern "C" void kernel_launch(void* const* d_in, const int* in_sizes, int n_in,
                              void* d_out, int out_size, void* d_ws, size_t ws_size,
                              hipStream_t stream) {
    const float* x      = (const float*)d_in[0];
    const float* hidden = (const float*)d_in[1];
    const float* Wq     = (const float*)d_in[2];
    const float* bq     = (const float*)d_in[3];
    const float* Wk     = (const float*)d_in[4];
    const float* bk     = (const float*)d_in[5];
    const float* Wv     = (const float*)d_in[6];
    const float* bv     = (const float*)d_in[7];
    float* out = (float*)d_out;
    int*   cnt = (int*)d_ws;   // 8 groups x 64-int stride

    hipMemsetAsync(cnt, 0, 16 * 64 * sizeof(int), stream);

    void* args[] = { (void*)&x, (void*)&hidden,
                     (void*)&Wq, (void*)&bq, (void*)&Wk, (void*)&bk,
                     (void*)&Wv, (void*)&bv, (void*)&out, (void*)&cnt };
    hipLaunchCooperativeKernel((const void*)rnn_persist,
                               dim3(NGROUP * WPG), dim3(THREADS),
                               args, 0, stream);
}

// Round 4
// 4265.973 us; speedup vs baseline: 18.1412x; 2.3858x over previous
//
#include <hip/hip_runtime.h>

// AttentionRnnBlock: N=16, T=2048, H=512.
// q|k|v = cat(x_t,h_t) @ W?.T + b? ; w=sigmoid(q*k); h' = (1-w)h + w tanh(v)
//
// Persistent cooperative kernel, 256 WGs x 512 threads, 1 WG/CU,
// __launch_bounds__(512,1) => 256-VGPR budget so weights truly pin.
//  - 8 groups x 32 WGs; group g owns batches {2g,2g+1}. All cross-WG data
//    moves via agent-scope (PoC) atomics -> placement-independent (G16).
//  - WG wm owns rows [wm*16,+16); wave wv owns rows jA=wm*16+2wv, jB=jA+1.
//  - lane owns cat slices x[lane*8,+8) and h[lane*8,+8): pinned weights
//    = 2 rows x 3 mats x (8 x-floats + 8 h-floats) = 96 floats (24 f4).
//  - per step: x-part FMAs (96, h-independent) run BEFORE the group wait to
//    hide exchange latency; then stage h_t (LDS, PoC dword loads), h-part
//    FMAs (96), split-butterfly reduce (21 shfl), gate on lanes 0-3, PoC
//    store of h_{t+1} into out[b,t+1,:] (out IS the exchange buffer).
//  - barrier: monotonic per-group counter, relaxed agent add/spin; ordering
//    via __syncthreads() vmcnt drain. No fences -> no cache maintenance.
#define N_B 16
#define T_S 2048
#define H_D 512
#define TH_F ((size_t)T_S * H_D)
#define NTH ((size_t)N_B * TH_F)
#define NGROUP 8
#define WPG 32
#define THREADS 512

__global__ __launch_bounds__(THREADS, 1) void rnn_persist(
    const float* __restrict__ x,
    const float* __restrict__ hidden,
    const float* __restrict__ Wq, const float* __restrict__ bq,
    const float* __restrict__ Wk, const float* __restrict__ bk,
    const float* __restrict__ Wv, const float* __restrict__ bv,
    float* __restrict__ out,
    int* __restrict__ cnt)
{
    const int tid  = threadIdx.x;
    const int lane = tid & 63;
    const int wv   = tid >> 6;          // wave 0..7
    const int g    = blockIdx.x & 7;    // group
    const int wm   = blockIdx.x >> 3;   // member 0..31
    const int b0 = 2 * g, b1 = 2 * g + 1;
    const int jA = wm * 16 + 2 * wv, jB = jA + 1;

    __shared__ __align__(16) float hs[2][H_D];   // h_t staging, 4 KB

    // ---- pin weights: [row][mat][c]; x-part and h-part slices of 8 floats
    float4 wx[2][3][2], wh[2][3][2];
    #pragma unroll
    for (int r = 0; r < 2; ++r) {
        const int j = jA + r;
        #pragma unroll
        for (int m = 0; m < 3; ++m) {
            const float* W = (m == 0) ? Wq : (m == 1) ? Wk : Wv;
            const float* base = W + (size_t)j * 1024 + lane * 8;
            wx[r][m][0] = *(const float4*)(base);
            wx[r][m][1] = *(const float4*)(base + 4);
            wh[r][m][0] = *(const float4*)(base + 512);
            wh[r][m][1] = *(const float4*)(base + 516);
        }
    }
    // writer-lane (lane<4) constants: bit0 = batch, bit1 = row
    const int jw = (lane & 2) ? jB : jA;
    const int bw = (lane & 1) ? b1 : b0;
    const float bqw = bq[jw], bkw = bk[jw], bvw = bv[jw];
    float ho = hidden[bw * H_D + jw];

    // h staging map: thread -> (batch half, 2 floats)
    const int h_nb  = tid >> 8;
    const int h_pos = (tid & 255) * 2;
    const int h_b   = h_nb ? b1 : b0;

    // ---- prologue: h_0 -> LDS; out[:,0,:] = h_0 (group's first WG only)
    {
        float v0 = hidden[h_b * H_D + h_pos];
        float v1 = hidden[h_b * H_D + h_pos + 1];
        *(float2*)&hs[h_nb][h_pos] = make_float2(v0, v1);
        if (wm == 0) {
            out[(size_t)h_b * TH_F + h_pos]     = v0;
            out[(size_t)h_b * TH_F + h_pos + 1] = v1;
        }
    }
    __syncthreads();

    // x lane-slice pointers (float4 granularity)
    const float4* xb0 = (const float4*)(x + (size_t)b0 * TH_F) + lane * 2;
    const float4* xb1 = (const float4*)(x + (size_t)b1 * TH_F) + lane * 2;
    float4 xv[2][2];
    xv[0][0] = xb0[0]; xv[0][1] = xb0[1];
    xv[1][0] = xb1[0]; xv[1][1] = xb1[1];

    int* mycnt = cnt + g * 64;

    for (int t = 0; t < T_S; ++t) {
        const bool do_next = (t + 1 < T_S);

        // ---- x-part FMAs (96) — independent of h_t, hides exchange latency
        float acc[2][3][2];
        #pragma unroll
        for (int r = 0; r < 2; ++r)
            #pragma unroll
            for (int m = 0; m < 3; ++m)
                #pragma unroll
                for (int nb = 0; nb < 2; ++nb) acc[r][m][nb] = 0.f;

        #pragma unroll
        for (int nb = 0; nb < 2; ++nb) {
            const float4 a0 = nb ? xv[1][0] : xv[0][0];
            const float4 a1 = nb ? xv[1][1] : xv[0][1];
            #pragma unroll
            for (int r = 0; r < 2; ++r)
                #pragma unroll
                for (int m = 0; m < 3; ++m) {
                    float s = acc[r][m][nb];
                    s = fmaf(wx[r][m][0].x, a0.x, s);
                    s = fmaf(wx[r][m][0].y, a0.y, s);
                    s = fmaf(wx[r][m][0].z, a0.z, s);
                    s = fmaf(wx[r][m][0].w, a0.w, s);
                    s = fmaf(wx[r][m][1].x, a1.x, s);
                    s = fmaf(wx[r][m][1].y, a1.y, s);
                    s = fmaf(wx[r][m][1].z, a1.z, s);
                    s = fmaf(wx[r][m][1].w, a1.w, s);
                    acc[r][m][nb] = s;
                }
        }

        // ---- prefetch x_{t+1} (in flight across the wait)
        if (do_next) {
            const size_t o = (size_t)(t + 1) * 128;
            xv[0][0] = xb0[o]; xv[0][1] = xb0[o + 1];
            xv[1][0] = xb1[o]; xv[1][1] = xb1[o + 1];
        }

        // ---- wait for h_t, stage into LDS (t>=1; t=0 staged in prologue)
        if (t > 0) {
            if (tid == 0) {
                const int target = WPG * t;
                while (__hip_atomic_load(mycnt, __ATOMIC_RELAXED,
                                         __HIP_MEMORY_SCOPE_AGENT) < target) {}
            }
            __syncthreads();
            const float* hsrc = out + (size_t)h_b * TH_F + (size_t)t * H_D + h_pos;
            float v0 = __hip_atomic_load(hsrc,     __ATOMIC_RELAXED, __HIP_MEMORY_SCOPE_AGENT);
            float v1 = __hip_atomic_load(hsrc + 1, __ATOMIC_RELAXED, __HIP_MEMORY_SCOPE_AGENT);
            *(float2*)&hs[h_nb][h_pos] = make_float2(v0, v1);
            __syncthreads();
        }

        // ---- h-part FMAs (96)
        #pragma unroll
        for (int nb = 0; nb < 2; ++nb) {
            const float4* hp = (const float4*)&hs[nb][0] + lane * 2;
            const float4 a0 = hp[0];
            const float4 a1 = hp[1];
            #pragma unroll
            for (int r = 0; r < 2; ++r)
                #pragma unroll
                for (int m = 0; m < 3; ++m) {
                    float s = acc[r][m][nb];
                    s = fmaf(wh[r][m][0].x, a0.x, s);
                    s = fmaf(wh[r][m][0].y, a0.y, s);
                    s = fmaf(wh[r][m][0].z, a0.z, s);
                    s = fmaf(wh[r][m][0].w, a0.w, s);
                    s = fmaf(wh[r][m][1].x, a1.x, s);
                    s = fmaf(wh[r][m][1].y, a1.y, s);
                    s = fmaf(wh[r][m][1].z, a1.z, s);
                    s = fmaf(wh[r][m][1].w, a1.w, s);
                    acc[r][m][nb] = s;
                }
        }

        // ---- split-butterfly reduce: 21 shfl instead of 72
        const bool lb0 = (lane & 1) != 0;   // batch specialization bit
        const bool lb1 = (lane & 2) != 0;   // row specialization bit
        float a6[2][3];
        #pragma unroll
        for (int r = 0; r < 2; ++r)
            #pragma unroll
            for (int m = 0; m < 3; ++m) {
                float keep = lb0 ? acc[r][m][1] : acc[r][m][0];
                float send = lb0 ? acc[r][m][0] : acc[r][m][1];
                a6[r][m] = keep + __shfl_xor(send, 1);
            }
        float a3[3];
        #pragma unroll
        for (int m = 0; m < 3; ++m) {
            float keep = lb1 ? a6[1][m] : a6[0][m];
            float send = lb1 ? a6[0][m] : a6[1][m];
            a3[m] = keep + __shfl_xor(send, 2);
        }
        #pragma unroll
        for (int s = 4; s < 64; s <<= 1) {
            a3[0] += __shfl_xor(a3[0], s);
            a3[1] += __shfl_xor(a3[1], s);
            a3[2] += __shfl_xor(a3[2], s);
        }

        // ---- gate + h_{t+1} store (writer lanes 0..3)
        if (lane < 4) {
            const float q = a3[0] + bqw;
            const float k = a3[1] + bkw;
            const float v = a3[2] + bvw;
            const float e  = __expf(-q * k);
            const float w  = __builtin_amdgcn_rcpf(1.f + e);
            const float ev = __expf(2.f * v);
            const float th = 1.f - 2.f * __builtin_amdgcn_rcpf(ev + 1.f);
            const float hn = fmaf(w, th - ho, ho);
            const size_t opos = do_next
                ? ((size_t)bw * TH_F + (size_t)(t + 1) * H_D + jw)
                : (NTH + (size_t)bw * H_D + jw);            // h_final tail
            __hip_atomic_store(out + opos, hn, __ATOMIC_RELAXED,
                               __HIP_MEMORY_SCOPE_AGENT);
            ho = hn;
        }

        // ---- signal: all 8 waves' stores drained (barrier), then +1
        __syncthreads();
        if (do_next && tid == 0)
            __hip_atomic_fetch_add(mycnt, 1, __ATOMIC_RELAXED,
                                   __HIP_MEMORY_SCOPE_AGENT);
    }
}

extern "C" void kernel_launch(void* const* d_in, const int* in_sizes, int n_in,
                              void* d_out, int out_size, void* d_ws, size_t ws_size,
                              hipStream_t stream) {
    const float* x      = (const float*)d_in[0];
    const float* hidden = (const float*)d_in[1];
    const float* Wq     = (const float*)d_in[2];
    const float* bq     = (const float*)d_in[3];
    const float* Wk     = (const float*)d_in[4];
    const float* bk     = (const float*)d_in[5];
    const float* Wv     = (const float*)d_in[6];
    const float* bv     = (const float*)d_in[7];
    float* out = (float*)d_out;
    int*   cnt = (int*)d_ws;   // 8 counters, 256B stride

    hipMemsetAsync(cnt, 0, 16 * 64 * sizeof(int), stream);

    void* args[] = { (void*)&x, (void*)&hidden,
                     (void*)&Wq, (void*)&bq, (void*)&Wk, (void*)&bk,
                     (void*)&Wv, (void*)&bv, (void*)&out, (void*)&cnt };
    hipLaunchCooperativeKernel((const void*)rnn_persist,
                               dim3(NGROUP * WPG), dim3(THREADS),
                               args, 0, stream);
}